// Round 7
// baseline (322.181 us; speedup 1.0000x reference)
//
#include <hip/hip_runtime.h>
#include <hip/hip_bf16.h>
#include <hip/hip_fp16.h>
#include <cstdint>
#include <cstddef>

// P=32, B=64, L=128, E=64, HB=128, HP=128, G=384, N=P*B=2048, PE=256, LH=128, NC=10

#define DINLINE __device__ __forceinline__

typedef _Float16 f16;
typedef f16 f16x8 __attribute__((ext_vector_type(8)));
typedef float f32x4 __attribute__((ext_vector_type(4)));

// raw-HW sigmoid/tanh: v_exp_f32 + v_rcp_f32 (1-ulp), no IEEE div sequence
static DINLINE float fast_sigmoid(float x) {
    const float e = __builtin_amdgcn_exp2f(-1.44269504089f * x);
    return __builtin_amdgcn_rcpf(1.0f + e);
}
static DINLINE float fast_tanh(float x) {
    const float e = __builtin_amdgcn_exp2f(2.88539008178f * x);
    return 1.0f - 2.0f * __builtin_amdgcn_rcpf(1.0f + e);
}

// LDS-only barrier: ds ops ordered, global loads/stores stay in flight (no vmcnt drain)
static DINLINE void lds_barrier() {
    asm volatile("s_waitcnt lgkmcnt(0)\n\ts_barrier" ::: "memory");
}

// ---------------------------------------------------------------------------
// K0a: byte tables, packed f16x4 {xr(+bhh_r), xz(+bhh_z), xn, 0} per (v, j).
// grid 512 (v=bx&255, dir=bx>>8), block 384.
__global__ void k_tables(const float* __restrict__ emb,
                         const float* __restrict__ wihF, const float* __restrict__ bihF,
                         const float* __restrict__ bhhF,
                         const float* __restrict__ wihB, const float* __restrict__ bihB,
                         const float* __restrict__ bhhB,
                         __half* __restrict__ tab4F, __half* __restrict__ tab4B) {
    const int v = blockIdx.x & 255;
    const int dir = blockIdx.x >> 8;
    const float* wih = dir ? wihB : wihF;
    const float* bih = dir ? bihB : bihF;
    const float* bhh = dir ? bhhB : bhhF;
    __half* tab4 = dir ? tab4B : tab4F;
    __shared__ float er[64];
    __shared__ float sh[384];
    if (threadIdx.x < 64) er[threadIdx.x] = emb[v * 64 + threadIdx.x];
    __syncthreads();
    const int g = threadIdx.x;  // 384 threads
    float acc = bih[g] + (g < 256 ? bhh[g] : 0.0f);
    #pragma unroll
    for (int e = 0; e < 64; ++e) acc = fmaf(wih[g * 64 + e], er[e], acc);
    sh[g] = acc;
    __syncthreads();
    if (g < 128) {
        f16 pk[4];
        pk[0] = (f16)sh[g];
        pk[1] = (f16)sh[g + 128];
        pk[2] = (f16)sh[g + 256];
        pk[3] = (f16)0.f;
        *reinterpret_cast<uint2*>(&tab4[(v * 128 + g) * 4]) =
            *reinterpret_cast<const uint2*>(pk);
    }
}

// ---------------------------------------------------------------------------
// K0b: transposes (2 matrices). out[c*R + r] = in[r*C + c]
struct TransArgs {
    const float* src[2];
    float* dst[2];
    int R[2];
    int C[2];
};
__global__ void k_transpose(TransArgs a) {
    const int m = blockIdx.y;
    const float* __restrict__ s = a.src[m];
    float* __restrict__ d = a.dst[m];
    const int R = a.R[m], C = a.C[m];
    const int total = R * C;
    for (int idx = blockIdx.x * blockDim.x + threadIdx.x; idx < total;
         idx += gridDim.x * blockDim.x) {
        const int r = idx / C, c = idx - r * C;
        d[c * R + r] = s[idx];
    }
}

// ---------------------------------------------------------------------------
// K2: byte BiGRU via MFMA f16, packed-f16x4 xg table + next-step prefetch +
// LDS-only barrier + register->global h store.
__global__ __launch_bounds__(512, 1) void k_byte_gru(
    const int* __restrict__ flow,
    const __half* __restrict__ tab4F, const __half* __restrict__ tab4B,
    const float* __restrict__ whhF, const float* __restrict__ whhB,
    const float* __restrict__ bhhF, const float* __restrict__ bhhB,
    __half* __restrict__ hF, __half* __restrict__ hB) {
    const int dir = blockIdx.x & 1;
    const int chunk = blockIdx.x >> 1;  // 0..127
    const int row0 = chunk * 16;
    const int tid = threadIdx.x;
    const int wid = tid >> 6;
    const int lane = tid & 63;
    const int c = lane & 15;
    const int q = lane >> 4;
    const int j = wid * 16 + c;  // h-col this lane produces

    const uint2* __restrict__ t4 =
        reinterpret_cast<const uint2*>(dir ? tab4B : tab4F);  // [v*128 + j]
    const float* __restrict__ whh = dir ? whhB : whhF;
    const float* __restrict__ bhh = dir ? bhhB : bhhF;
    __half* __restrict__ hout = dir ? hB : hF;

    __shared__ f16 hbuf[2][16 * 128];  // swizzled: row*128 + (k ^ ((row&7)<<3))
    __shared__ int flow_lds[16][128];

    for (int i = tid; i < 16 * 128; i += 512)
        flow_lds[i >> 7][i & 127] = flow[row0 * 128 + i] & 255;
    for (int i = tid; i < 16 * 128; i += 512) hbuf[0][i] = (f16)0.f;

    // B fragments: B[k][col] = whh[(g*128+j)][k]; lane: col=lane&15, k=(lane>>4)*8+e+ks*32
    f16x8 Bf[3][4];
    #pragma unroll
    for (int g = 0; g < 3; ++g) {
        #pragma unroll
        for (int ks = 0; ks < 4; ++ks) {
            const float* src = whh + (size_t)(g * 128 + j) * 128 + ks * 32 + q * 8;
            f16x8 b;
            #pragma unroll
            for (int e = 0; e < 8; ++e) b[e] = (f16)src[e];
            Bf[g][ks] = b;
        }
    }
    const float bh2 = bhh[j + 256];  // r,z biases folded into tab4
    float hold[4];
    #pragma unroll
    for (int rr = 0; rr < 4; ++rr) hold[rr] = 0.f;
    __syncthreads();

    // preload xg for t=0
    uint2 xg[4];
    {
        const int tt0 = dir ? 127 : 0;
        #pragma unroll
        for (int rr = 0; rr < 4; ++rr)
            xg[rr] = t4[flow_lds[q * 4 + rr][tt0] * 128 + j];
    }

    #pragma unroll 2
    for (int t = 0; t < 128; ++t) {
        const int curb = t & 1, nxtb = curb ^ 1;
        const int tt = dir ? (127 - t) : t;

        // A fragments (row = c, k = ks*32 + q*8 + e, swizzled)
        f16x8 Af[4];
        #pragma unroll
        for (int ks = 0; ks < 4; ++ks) {
            const int kb = ks * 32 + q * 8;
            const int idx = c * 128 + (kb ^ ((c & 7) << 3));
            Af[ks] = *reinterpret_cast<const f16x8*>(&hbuf[curb][idx]);
        }

        // prefetch next step's xg (L2 latency hides under MFMA + gates)
        uint2 xgn[4];
        if (t < 127) {
            const int ttn = dir ? (126 - t) : (t + 1);
            #pragma unroll
            for (int rr = 0; rr < 4; ++rr)
                xgn[rr] = t4[flow_lds[q * 4 + rr][ttn] * 128 + j];
        }

        f32x4 a0 = {0.f, 0.f, 0.f, 0.f};
        f32x4 a1 = {0.f, 0.f, 0.f, 0.f};
        f32x4 a2 = {0.f, 0.f, 0.f, 0.f};
        #pragma unroll
        for (int ks = 0; ks < 4; ++ks) {
            a0 = __builtin_amdgcn_mfma_f32_16x16x32_f16(Af[ks], Bf[0][ks], a0, 0, 0, 0);
            a1 = __builtin_amdgcn_mfma_f32_16x16x32_f16(Af[ks], Bf[1][ks], a1, 0, 0, 0);
            a2 = __builtin_amdgcn_mfma_f32_16x16x32_f16(Af[ks], Bf[2][ks], a2, 0, 0, 0);
        }

        #pragma unroll
        for (int rr = 0; rr < 4; ++rr) {
            const f16* xp = reinterpret_cast<const f16*>(&xg[rr]);
            const float rg = fast_sigmoid((float)xp[0] + a0[rr]);
            const float zg = fast_sigmoid((float)xp[1] + a1[rr]);
            const float ng = fast_tanh((float)xp[2] + rg * (a2[rr] + bh2));
            const float hn = fmaf(zg, hold[rr] - ng, ng);
            hold[rr] = hn;
            const int row = q * 4 + rr;
            hbuf[nxtb][row * 128 + (j ^ ((row & 7) << 3))] = (f16)hn;
            hout[((size_t)tt * 2048 + row0 + row) * 128 + j] = (__half)hn;
        }
        lds_barrier();
        #pragma unroll
        for (int rr = 0; rr < 4; ++rr) xg[rr] = xgn[rr];
    }
}

// ---------------------------------------------------------------------------
// K3: byte attention scores + softmax fused.
// grid 512 (512 positions = 8 softmax groups each), block 256 (4 waves).
__global__ __launch_bounds__(256, 1) void k_scores_attn(
    const __half* __restrict__ hF, const __half* __restrict__ hB,
    const float* __restrict__ w1,  // [128][256] row-major (= B[col][k])
    const float* __restrict__ b1, const float* __restrict__ w2,
    const float* __restrict__ b2, float* __restrict__ attn) {
    __shared__ f16 w1lds[128 * 256];  // 64 KB, swizzled col*256 + (k ^ ((col&7)<<3))
    __shared__ float sc[128];
    const int tid = threadIdx.x;
    for (int i = tid; i < 128 * 256; i += 256) {
        const int col = i >> 8, k = i & 255;
        w1lds[col * 256 + (k ^ ((col & 7) << 3))] = (f16)w1[i];
    }
    const int lane = tid & 63, w = tid >> 6;
    const int c = lane & 15, q = lane >> 4;

    float b1v[8], w2v[8];
    #pragma unroll
    for (int ct = 0; ct < 8; ++ct) {
        b1v[ct] = b1[ct * 16 + c];
        w2v[ct] = w2[ct * 16 + c];
    }
    const float b2v = b2[0];
    __syncthreads();

    for (int it = 0; it < 4; ++it) {
        const int pos0 = blockIdx.x * 512 + it * 128;

        // wave w: position tiles pt = 2w, 2w+1 (16 positions each)
        f16x8 Af[2][8];
        #pragma unroll
        for (int pt = 0; pt < 2; ++pt) {
            const size_t pos = (size_t)pos0 + (w * 2 + pt) * 16 + c;
            const f16* hFp = (const f16*)(hF + pos * 128);
            const f16* hBp = (const f16*)(hB + pos * 128);
            #pragma unroll
            for (int ks = 0; ks < 4; ++ks)
                Af[pt][ks] = *reinterpret_cast<const f16x8*>(hFp + ks * 32 + q * 8);
            #pragma unroll
            for (int ks = 0; ks < 4; ++ks)
                Af[pt][4 + ks] = *reinterpret_cast<const f16x8*>(hBp + ks * 32 + q * 8);
        }

        float s[2][4] = {{0.f, 0.f, 0.f, 0.f}, {0.f, 0.f, 0.f, 0.f}};
        #pragma unroll
        for (int ct = 0; ct < 8; ++ct) {
            const int jj = ct * 16 + c;
            f16x8 Bfr[8];
            #pragma unroll
            for (int ks = 0; ks < 8; ++ks) {
                const int k = ks * 32 + q * 8;
                Bfr[ks] = *reinterpret_cast<const f16x8*>(
                    &w1lds[jj * 256 + (k ^ ((jj & 7) << 3))]);
            }
            #pragma unroll
            for (int pt = 0; pt < 2; ++pt) {
                f32x4 acc = {0.f, 0.f, 0.f, 0.f};
                #pragma unroll
                for (int ks = 0; ks < 8; ++ks)
                    acc = __builtin_amdgcn_mfma_f32_16x16x32_f16(Af[pt][ks],
                                                                 Bfr[ks], acc,
                                                                 0, 0, 0);
                #pragma unroll
                for (int rr = 0; rr < 4; ++rr)
                    s[pt][rr] += w2v[ct] * fast_tanh(acc[rr] + b1v[ct]);
            }
        }
        #pragma unroll
        for (int pt = 0; pt < 2; ++pt) {
            #pragma unroll
            for (int rr = 0; rr < 4; ++rr) {
                float v = s[pt][rr];
                v += __shfl_xor(v, 1);
                v += __shfl_xor(v, 2);
                v += __shfl_xor(v, 4);
                v += __shfl_xor(v, 8);
                if (c == 0) sc[(w * 2 + pt) * 16 + q * 4 + rr] = v + b2v;
            }
        }
        __syncthreads();
        // softmax over b: two groups of 64
        if (tid < 128) {
            const float sv = sc[tid];
            float m = sv;
            for (int off = 32; off; off >>= 1) m = fmaxf(m, __shfl_xor(m, off));
            const float e = __expf(sv - m);
            float sum = e;
            for (int off = 32; off; off >>= 1) sum += __shfl_xor(sum, off);
            attn[pos0 + tid] = e / sum;
        }
        __syncthreads();
    }
}

// ---------------------------------------------------------------------------
// K3b: packet_emb[n,d] = sum_l attn[l,n] * h[l,n,d]. grid 512 (4 n each), block 256.
__global__ __launch_bounds__(256) void k_packet_emb(
    const __half* __restrict__ hF, const __half* __restrict__ hB,
    const float* __restrict__ attn, float* __restrict__ pe) {
    const int tid = threadIdx.x;
    const int g = tid >> 6;          // n group
    const int lane = tid & 63;
    const int n = blockIdx.x * 4 + g;
    const bool isF = lane < 32;
    const int chunk = lane & 31;     // 4 f16 per chunk
    const __half* __restrict__ hsrc = (isF ? hF : hB) + (size_t)n * 128 + chunk * 4;
    float acc0 = 0.f, acc1 = 0.f, acc2 = 0.f, acc3 = 0.f;
    #pragma unroll 4
    for (int l = 0; l < 128; ++l) {
        const float wv = attn[l * 2048 + n];
        const uint2 u = *reinterpret_cast<const uint2*>(hsrc + (size_t)l * 2048 * 128);
        const f16* hv = reinterpret_cast<const f16*>(&u);
        acc0 = fmaf(wv, (float)hv[0], acc0);
        acc1 = fmaf(wv, (float)hv[1], acc1);
        acc2 = fmaf(wv, (float)hv[2], acc2);
        acc3 = fmaf(wv, (float)hv[3], acc3);
    }
    float4 o = {acc0, acc1, acc2, acc3};
    *reinterpret_cast<float4*>(&pe[n * 256 + (isF ? 0 : 128) + chunk * 4]) = o;
}

// ---------------------------------------------------------------------------
// K4pre: xg2[p,n,g] = b_ih[g] (+b_hh r/z) + sum_d pe[p,n,d]*w_ih[g,d].
// grid (256,2), block 384.
__global__ __launch_bounds__(384) void k_pkt_xg(
    const float* __restrict__ pe, const float* __restrict__ wihTF,
    const float* __restrict__ bihF, const float* __restrict__ bhhF,
    const float* __restrict__ wihTB, const float* __restrict__ bihB,
    const float* __restrict__ bhhB, float* __restrict__ xgF,
    float* __restrict__ xgB) {
    const int dir = blockIdx.y;
    const float* __restrict__ wihT = dir ? wihTB : wihTF;
    const float* __restrict__ bih = dir ? bihB : bihF;
    const float* __restrict__ bhh = dir ? bhhB : bhhF;
    float* __restrict__ xg = dir ? xgB : xgF;
    const int rbase = blockIdx.x * 8;
    __shared__ float xrow[8][256];
    for (int i = threadIdx.x; i < 8 * 256; i += 384)
        xrow[i >> 8][i & 255] = pe[rbase * 256 + i];
    __syncthreads();
    const int g = threadIdx.x;
    float acc[8];
    const float bias = bih[g] + (g < 256 ? bhh[g] : 0.0f);
    #pragma unroll
    for (int r = 0; r < 8; ++r) acc[r] = bias;
    for (int d = 0; d < 256; ++d) {
        const float w = wihT[d * 384 + g];
        #pragma unroll
        for (int r = 0; r < 8; ++r) acc[r] = fmaf(w, xrow[r][d], acc[r]);
    }
    #pragma unroll
    for (int r = 0; r < 8; ++r) xg[(rbase + r) * 384 + g] = acc[r];
}

// ---------------------------------------------------------------------------
// K4: packet BiGRU via MFMA f16. grid 8 (dir=bx&1, chunk=bx>>1: 16 rows),
// block 512 (8 waves), 32 steps.
__global__ __launch_bounds__(512, 1) void k_pkt_gru(
    const float* __restrict__ xgF, const float* __restrict__ xgB,
    const float* __restrict__ whhF, const float* __restrict__ whhB,
    const float* __restrict__ bhhF, const float* __restrict__ bhhB,
    float* __restrict__ h2F, float* __restrict__ h2B) {
    const int dir = blockIdx.x & 1;
    const int chunk = blockIdx.x >> 1;  // 0..3
    const int row0 = chunk * 16;
    const int tid = threadIdx.x;
    const int wid = tid >> 6;
    const int lane = tid & 63;
    const int c = lane & 15;
    const int q = lane >> 4;
    const int j = wid * 16 + c;

    const float* __restrict__ xg = dir ? xgB : xgF;
    const float* __restrict__ whh = dir ? whhB : whhF;
    const float* __restrict__ bhh = dir ? bhhB : bhhF;
    float* __restrict__ hout = dir ? h2B : h2F;

    __shared__ f16 hbuf[2][16 * 128];  // swizzled: row*128 + (k ^ ((row&7)<<3))

    for (int i = tid; i < 16 * 128; i += 512) hbuf[0][i] = (f16)0.f;

    f16x8 Bf[3][4];
    #pragma unroll
    for (int g = 0; g < 3; ++g) {
        #pragma unroll
        for (int ks = 0; ks < 4; ++ks) {
            const float* src = whh + (size_t)(g * 128 + j) * 128 + ks * 32 + q * 8;
            f16x8 b;
            #pragma unroll
            for (int e = 0; e < 8; ++e) b[e] = (f16)src[e];
            Bf[g][ks] = b;
        }
    }
    const float bh2 = bhh[j + 256];  // r,z biases folded into xg
    float hold[4];
    #pragma unroll
    for (int rr = 0; rr < 4; ++rr) hold[rr] = 0.f;
    __syncthreads();

    for (int t = 0; t < 32; ++t) {
        const int curb = t & 1, nxtb = curb ^ 1;
        const int tt = dir ? (31 - t) : t;

        float xr[4], xz[4], xn[4];
        #pragma unroll
        for (int rr = 0; rr < 4; ++rr) {
            const float* xp = xg + ((size_t)tt * 64 + row0 + q * 4 + rr) * 384 + j;
            xr[rr] = xp[0];
            xz[rr] = xp[128];
            xn[rr] = xp[256];
        }

        f16x8 Af[4];
        #pragma unroll
        for (int ks = 0; ks < 4; ++ks) {
            const int kb = ks * 32 + q * 8;
            const int idx = c * 128 + (kb ^ ((c & 7) << 3));
            Af[ks] = *reinterpret_cast<const f16x8*>(&hbuf[curb][idx]);
        }

        f32x4 a0 = {0.f, 0.f, 0.f, 0.f};
        f32x4 a1 = {0.f, 0.f, 0.f, 0.f};
        f32x4 a2 = {0.f, 0.f, 0.f, 0.f};
        #pragma unroll
        for (int ks = 0; ks < 4; ++ks) {
            a0 = __builtin_amdgcn_mfma_f32_16x16x32_f16(Af[ks], Bf[0][ks], a0, 0, 0, 0);
            a1 = __builtin_amdgcn_mfma_f32_16x16x32_f16(Af[ks], Bf[1][ks], a1, 0, 0, 0);
            a2 = __builtin_amdgcn_mfma_f32_16x16x32_f16(Af[ks], Bf[2][ks], a2, 0, 0, 0);
        }

        #pragma unroll
        for (int rr = 0; rr < 4; ++rr) {
            const float rg = fast_sigmoid(xr[rr] + a0[rr]);
            const float zg = fast_sigmoid(xz[rr] + a1[rr]);
            const float ng = fast_tanh(xn[rr] + rg * (a2[rr] + bh2));
            const float hn = fmaf(zg, hold[rr] - ng, ng);
            hold[rr] = hn;
            const int row = q * 4 + rr;
            hbuf[nxtb][row * 128 + (j ^ ((row & 7) << 3))] = (f16)hn;
            hout[((size_t)tt * 64 + row0 + row) * 128 + j] = hn;
        }
        lds_barrier();
    }
}

// ---------------------------------------------------------------------------
// K5a: packet attention scores. grid 2048 (n), block 128.
__global__ __launch_bounds__(128) void k_scores2(
    const float* __restrict__ h2F, const float* __restrict__ h2B,
    const float* __restrict__ paw1,  // [128][256] row-major
    const float* __restrict__ pab1, const float* __restrict__ paw2,
    const float* __restrict__ pab2, float* __restrict__ scores2) {
    const int n = blockIdx.x;
    const int tid = threadIdx.x;  // 128
    __shared__ float x[256];
    __shared__ float red[2];
    x[tid] = h2F[n * 128 + tid];
    x[tid + 128] = h2B[n * 128 + tid];
    __syncthreads();
    float acc = pab1[tid];
    const float* wr = paw1 + tid * 256;
    #pragma unroll 8
    for (int d = 0; d < 256; ++d) acc = fmaf(wr[d], x[d], acc);
    float s = paw2[tid] * fast_tanh(acc);
    s += __shfl_xor(s, 1);
    s += __shfl_xor(s, 2);
    s += __shfl_xor(s, 4);
    s += __shfl_xor(s, 8);
    s += __shfl_xor(s, 16);
    s += __shfl_xor(s, 32);
    if ((tid & 63) == 0) red[tid >> 6] = s;
    __syncthreads();
    if (tid == 0) scores2[n] = red[0] + red[1] + pab2[0];
}

// ---------------------------------------------------------------------------
// K5b: softmax over b + weighted sum + final FC. grid 32 (p), block 256.
__global__ __launch_bounds__(256) void k_final3(
    const float* __restrict__ h2F, const float* __restrict__ h2B,
    const float* __restrict__ scores2, const float* __restrict__ wf,
    const float* __restrict__ bfv, float* __restrict__ outp) {
    const int p = blockIdx.x;
    const int tid = threadIdx.x;
    __shared__ float sc[64];
    __shared__ float femb[256];
    __shared__ float red[64];

    if (tid < 64) {
        const float s = scores2[p * 64 + tid];
        float m = s;
        for (int off = 32; off; off >>= 1) m = fmaxf(m, __shfl_xor(m, off));
        const float e = __expf(s - m);
        float sum = e;
        for (int off = 32; off; off >>= 1) sum += __shfl_xor(sum, off);
        sc[tid] = e / sum;
    }
    __syncthreads();

    {
        const float* __restrict__ hsrc = (tid < 128) ? h2F : h2B;
        const int d = tid & 127;
        float acc = 0.f;
        for (int b = 0; b < 64; ++b)
            acc = fmaf(sc[b], hsrc[(p * 64 + b) * 128 + d], acc);
        femb[tid] = acc;
    }
    __syncthreads();

    const float fv = femb[tid];
    #pragma unroll
    for (int c = 0; c < 10; ++c) {
        float s = fv * wf[c * 256 + tid];
        s += __shfl_xor(s, 1);
        s += __shfl_xor(s, 2);
        s += __shfl_xor(s, 4);
        s += __shfl_xor(s, 8);
        s += __shfl_xor(s, 16);
        s += __shfl_xor(s, 32);
        if ((tid & 63) == 0) red[(c << 2) | (tid >> 6)] = s;
        __syncthreads();
        if (tid == 0)
            outp[p * 10 + c] = bfv[c] + red[c << 2] + red[(c << 2) | 1] +
                               red[(c << 2) | 2] + red[(c << 2) | 3];
        __syncthreads();
    }
}

// ---------------------------------------------------------------------------
extern "C" void kernel_launch(void* const* d_in, const int* in_sizes, int n_in,
                              void* d_out, int out_size, void* d_ws,
                              size_t ws_size, hipStream_t stream) {
    const int* flow = (const int*)d_in[0];
    const float* emb = (const float*)d_in[1];
    const float* byte_wih_f = (const float*)d_in[2];
    const float* byte_whh_f = (const float*)d_in[3];
    const float* byte_bih_f = (const float*)d_in[4];
    const float* byte_bhh_f = (const float*)d_in[5];
    const float* byte_wih_b = (const float*)d_in[6];
    const float* byte_whh_b = (const float*)d_in[7];
    const float* byte_bih_b = (const float*)d_in[8];
    const float* byte_bhh_b = (const float*)d_in[9];
    const float* pkt_wih_f = (const float*)d_in[10];
    const float* pkt_whh_f = (const float*)d_in[11];
    const float* pkt_bih_f = (const float*)d_in[12];
    const float* pkt_bhh_f = (const float*)d_in[13];
    const float* pkt_wih_b = (const float*)d_in[14];
    const float* pkt_whh_b = (const float*)d_in[15];
    const float* pkt_bih_b = (const float*)d_in[16];
    const float* pkt_bhh_b = (const float*)d_in[17];
    const float* ba_w1 = (const float*)d_in[18];
    const float* ba_b1 = (const float*)d_in[19];
    const float* ba_w2 = (const float*)d_in[20];
    const float* ba_b2 = (const float*)d_in[21];
    const float* pa_w1 = (const float*)d_in[22];
    const float* pa_b1 = (const float*)d_in[23];
    const float* pa_w2 = (const float*)d_in[24];
    const float* pa_b2 = (const float*)d_in[25];
    const float* wf = (const float*)d_in[26];
    const float* bf = (const float*)d_in[27];

    char* base = (char*)d_ws;
    size_t off = 0;
    auto allocf = [&](size_t nf) -> float* {
        float* p = (float*)(base + off);
        off += nf * sizeof(float);
        return p;
    };
    auto alloch = [&](size_t nh) -> __half* {
        off = (off + 255) & ~(size_t)255;
        __half* p = (__half*)(base + off);
        off += nh * sizeof(__half);
        return p;
    };
    float* wihTpF = allocf(256 * 384);
    float* wihTpB = allocf(256 * 384);
    float* attn = allocf(262144);
    float* pe = allocf(2048 * 256);
    float* xgF = allocf(32 * 64 * 384);
    float* xgB = allocf(32 * 64 * 384);
    float* h2F = allocf(32 * 64 * 128);
    float* h2B = allocf(32 * 64 * 128);
    float* scores2 = allocf(2048);
    __half* tab4F = alloch(256 * 128 * 4);
    __half* tab4B = alloch(256 * 128 * 4);
    __half* hF = alloch((size_t)128 * 2048 * 128);
    __half* hB = alloch((size_t)128 * 2048 * 128);
    if (off > ws_size) return;  // diagnostic: leaves d_out poisoned
    (void)in_sizes; (void)n_in; (void)out_size;

    k_tables<<<512, 384, 0, stream>>>(emb, byte_wih_f, byte_bih_f, byte_bhh_f,
                                      byte_wih_b, byte_bih_b, byte_bhh_b,
                                      tab4F, tab4B);

    TransArgs ta;
    ta.src[0] = pkt_wih_f; ta.dst[0] = wihTpF; ta.R[0] = 384; ta.C[0] = 256;
    ta.src[1] = pkt_wih_b; ta.dst[1] = wihTpB; ta.R[1] = 384; ta.C[1] = 256;
    k_transpose<<<dim3(96, 2), 256, 0, stream>>>(ta);

    k_byte_gru<<<256, 512, 0, stream>>>(flow, tab4F, tab4B, byte_whh_f,
                                        byte_whh_b, byte_bhh_f, byte_bhh_b, hF,
                                        hB);

    k_scores_attn<<<512, 256, 0, stream>>>(hF, hB, ba_w1, ba_b1, ba_w2, ba_b2,
                                           attn);
    k_packet_emb<<<512, 256, 0, stream>>>(hF, hB, attn, pe);

    k_pkt_xg<<<dim3(256, 2), 384, 0, stream>>>(pe, wihTpF, pkt_bih_f,
                                               pkt_bhh_f, wihTpB, pkt_bih_b,
                                               pkt_bhh_b, xgF, xgB);
    k_pkt_gru<<<8, 512, 0, stream>>>(xgF, xgB, pkt_whh_f, pkt_whh_b,
                                     pkt_bhh_f, pkt_bhh_b, h2F, h2B);
    k_scores2<<<2048, 128, 0, stream>>>(h2F, h2B, pa_w1, pa_b1, pa_w2, pa_b2,
                                        scores2);
    k_final3<<<32, 256, 0, stream>>>(h2F, h2B, scores2, wf, bf, (float*)d_out);
}

// Round 8
// 288.435 us; speedup vs baseline: 1.1170x; 1.1170x over previous
//
#include <hip/hip_runtime.h>
#include <hip/hip_bf16.h>
#include <hip/hip_fp16.h>
#include <cstdint>
#include <cstddef>

// P=32, B=64, L=128, E=64, HB=128, HP=128, G=384, N=P*B=2048, PE=256, LH=128, NC=10

#define DINLINE __device__ __forceinline__

typedef _Float16 f16;
typedef f16 f16x8 __attribute__((ext_vector_type(8)));
typedef float f32x4 __attribute__((ext_vector_type(4)));

// raw-HW sigmoid/tanh: v_exp_f32 + v_rcp_f32 (1-ulp), no IEEE div sequence
static DINLINE float fast_sigmoid(float x) {
    const float e = __builtin_amdgcn_exp2f(-1.44269504089f * x);
    return __builtin_amdgcn_rcpf(1.0f + e);
}
static DINLINE float fast_tanh(float x) {
    const float e = __builtin_amdgcn_exp2f(2.88539008178f * x);
    return 1.0f - 2.0f * __builtin_amdgcn_rcpf(1.0f + e);
}

// LDS-only barrier: ds ops ordered, global stores stay in flight (no vmcnt drain)
static DINLINE void lds_barrier() {
    asm volatile("s_waitcnt lgkmcnt(0)\n\ts_barrier" ::: "memory");
    __builtin_amdgcn_sched_barrier(0);
}

// ---------------------------------------------------------------------------
// K0a: byte tables, packed float4 {xr(+bhh_r), xz(+bhh_z), xn, 0} per (v, j).
// grid 512 (v=bx&255, dir=bx>>8), block 384.
__global__ void k_tables(const float* __restrict__ emb,
                         const float* __restrict__ wihF, const float* __restrict__ bihF,
                         const float* __restrict__ bhhF,
                         const float* __restrict__ wihB, const float* __restrict__ bihB,
                         const float* __restrict__ bhhB,
                         float4* __restrict__ tab4F, float4* __restrict__ tab4B) {
    const int v = blockIdx.x & 255;
    const int dir = blockIdx.x >> 8;
    const float* wih = dir ? wihB : wihF;
    const float* bih = dir ? bihB : bihF;
    const float* bhh = dir ? bhhB : bhhF;
    float4* tab4 = dir ? tab4B : tab4F;
    __shared__ float er[64];
    __shared__ float sh[384];
    if (threadIdx.x < 64) er[threadIdx.x] = emb[v * 64 + threadIdx.x];
    __syncthreads();
    const int g = threadIdx.x;  // 384 threads
    float acc = bih[g] + (g < 256 ? bhh[g] : 0.0f);
    #pragma unroll
    for (int e = 0; e < 64; ++e) acc = fmaf(wih[g * 64 + e], er[e], acc);
    sh[g] = acc;
    __syncthreads();
    if (g < 128) {
        float4 pk;
        pk.x = sh[g];
        pk.y = sh[g + 128];
        pk.z = sh[g + 256];
        pk.w = 0.f;
        tab4[v * 128 + g] = pk;
    }
}

// ---------------------------------------------------------------------------
// K0b: transposes (2 matrices). out[c*R + r] = in[r*C + c]
struct TransArgs {
    const float* src[2];
    float* dst[2];
    int R[2];
    int C[2];
};
__global__ void k_transpose(TransArgs a) {
    const int m = blockIdx.y;
    const float* __restrict__ s = a.src[m];
    float* __restrict__ d = a.dst[m];
    const int R = a.R[m], C = a.C[m];
    const int total = R * C;
    for (int idx = blockIdx.x * blockDim.x + threadIdx.x; idx < total;
         idx += gridDim.x * blockDim.x) {
        const int r = idx / C, c = idx - r * C;
        d[c * R + r] = s[idx];
    }
}

// ---------------------------------------------------------------------------
// K2: byte BiGRU via MFMA f16. float4 xg table, staged coalesced store,
// LDS-only barrier (global stores pipeline across steps).
__global__ __launch_bounds__(512, 1) void k_byte_gru(
    const int* __restrict__ flow,
    const float4* __restrict__ tab4F, const float4* __restrict__ tab4B,
    const float* __restrict__ whhF, const float* __restrict__ whhB,
    const float* __restrict__ bhhF, const float* __restrict__ bhhB,
    __half* __restrict__ hF, __half* __restrict__ hB) {
    const int dir = blockIdx.x & 1;
    const int chunk = blockIdx.x >> 1;  // 0..127
    const int row0 = chunk * 16;
    const int tid = threadIdx.x;
    const int wid = tid >> 6;
    const int lane = tid & 63;
    const int c = lane & 15;
    const int q = lane >> 4;
    const int j = wid * 16 + c;  // h-col this lane produces

    const float4* __restrict__ t4 = dir ? tab4B : tab4F;  // [v*128 + j]
    const float* __restrict__ whh = dir ? whhB : whhF;
    const float* __restrict__ bhh = dir ? bhhB : bhhF;
    __half* __restrict__ hout = dir ? hB : hF;

    __shared__ f16 hbuf[2][16 * 128];  // swizzled: row*128 + (k ^ ((row&7)<<3))
    __shared__ int flow_lds[16][128];

    for (int i = tid; i < 16 * 128; i += 512)
        flow_lds[i >> 7][i & 127] = flow[row0 * 128 + i] & 255;
    for (int i = tid; i < 16 * 128; i += 512) hbuf[0][i] = (f16)0.f;

    // B fragments: B[k][col] = whh[(g*128+j)][k]; lane: col=lane&15, k=(lane>>4)*8+e+ks*32
    f16x8 Bf[3][4];
    #pragma unroll
    for (int g = 0; g < 3; ++g) {
        #pragma unroll
        for (int ks = 0; ks < 4; ++ks) {
            const float* src = whh + (size_t)(g * 128 + j) * 128 + ks * 32 + q * 8;
            f16x8 b;
            #pragma unroll
            for (int e = 0; e < 8; ++e) b[e] = (f16)src[e];
            Bf[g][ks] = b;
        }
    }
    const float bh2 = bhh[j + 256];  // r,z biases folded into tab4
    float hold[4];
    #pragma unroll
    for (int rr = 0; rr < 4; ++rr) hold[rr] = 0.f;
    __syncthreads();

    for (int t = 0; t < 128; ++t) {
        const int curb = t & 1, nxtb = curb ^ 1;
        const int tt = dir ? (127 - t) : t;

        // xg gathers (issued before the MFMA-dependent chain; 16 lanes
        // consecutive j -> 256B coalesced runs in L2)
        float4 x4[4];
        #pragma unroll
        for (int rr = 0; rr < 4; ++rr)
            x4[rr] = t4[flow_lds[q * 4 + rr][tt] * 128 + j];

        // A fragments (row = c, k = ks*32 + q*8 + e, swizzled)
        f16x8 Af[4];
        #pragma unroll
        for (int ks = 0; ks < 4; ++ks) {
            const int kb = ks * 32 + q * 8;
            const int idx = c * 128 + (kb ^ ((c & 7) << 3));
            Af[ks] = *reinterpret_cast<const f16x8*>(&hbuf[curb][idx]);
        }

        f32x4 a0 = {0.f, 0.f, 0.f, 0.f};
        f32x4 a1 = {0.f, 0.f, 0.f, 0.f};
        f32x4 a2 = {0.f, 0.f, 0.f, 0.f};
        #pragma unroll
        for (int ks = 0; ks < 4; ++ks) {
            a0 = __builtin_amdgcn_mfma_f32_16x16x32_f16(Af[ks], Bf[0][ks], a0, 0, 0, 0);
            a1 = __builtin_amdgcn_mfma_f32_16x16x32_f16(Af[ks], Bf[1][ks], a1, 0, 0, 0);
            a2 = __builtin_amdgcn_mfma_f32_16x16x32_f16(Af[ks], Bf[2][ks], a2, 0, 0, 0);
        }

        #pragma unroll
        for (int rr = 0; rr < 4; ++rr) {
            const float rg = fast_sigmoid(x4[rr].x + a0[rr]);
            const float zg = fast_sigmoid(x4[rr].y + a1[rr]);
            const float ng = fast_tanh(x4[rr].z + rg * (a2[rr] + bh2));
            const float hn = fmaf(zg, hold[rr] - ng, ng);
            hold[rr] = hn;
            const int row = q * 4 + rr;
            hbuf[nxtb][row * 128 + (j ^ ((row & 7) << 3))] = (f16)hn;
        }
        lds_barrier();

        // coalesced global store of this step's h from hbuf[nxtb]
        // (store stays in flight across the next lds_barrier - never drained)
        {
            const int row = tid >> 5;
            const int ho = (tid & 31) * 4;
            const int idx = row * 128 + (ho ^ ((row & 7) << 3));
            const uint2 v = *reinterpret_cast<const uint2*>(&hbuf[nxtb][idx]);
            *reinterpret_cast<uint2*>(
                &hout[((size_t)tt * 2048 + row0 + row) * 128 + ho]) = v;
        }
    }
}

// ---------------------------------------------------------------------------
// K3: byte attention scores + softmax fused.
// grid 512 (512 positions = 8 softmax groups each), block 256 (4 waves).
__global__ __launch_bounds__(256, 1) void k_scores_attn(
    const __half* __restrict__ hF, const __half* __restrict__ hB,
    const float* __restrict__ w1,  // [128][256] row-major (= B[col][k])
    const float* __restrict__ b1, const float* __restrict__ w2,
    const float* __restrict__ b2, float* __restrict__ attn) {
    __shared__ f16 w1lds[128 * 256];  // 64 KB, swizzled col*256 + (k ^ ((col&7)<<3))
    __shared__ float sc[128];
    const int tid = threadIdx.x;
    for (int i = tid; i < 128 * 256; i += 256) {
        const int col = i >> 8, k = i & 255;
        w1lds[col * 256 + (k ^ ((col & 7) << 3))] = (f16)w1[i];
    }
    const int lane = tid & 63, w = tid >> 6;
    const int c = lane & 15, q = lane >> 4;

    float b1v[8], w2v[8];
    #pragma unroll
    for (int ct = 0; ct < 8; ++ct) {
        b1v[ct] = b1[ct * 16 + c];
        w2v[ct] = w2[ct * 16 + c];
    }
    const float b2v = b2[0];
    __syncthreads();

    for (int it = 0; it < 4; ++it) {
        const int pos0 = blockIdx.x * 512 + it * 128;

        // wave w: position tiles pt = 2w, 2w+1 (16 positions each)
        f16x8 Af[2][8];
        #pragma unroll
        for (int pt = 0; pt < 2; ++pt) {
            const size_t pos = (size_t)pos0 + (w * 2 + pt) * 16 + c;
            const f16* hFp = (const f16*)(hF + pos * 128);
            const f16* hBp = (const f16*)(hB + pos * 128);
            #pragma unroll
            for (int ks = 0; ks < 4; ++ks)
                Af[pt][ks] = *reinterpret_cast<const f16x8*>(hFp + ks * 32 + q * 8);
            #pragma unroll
            for (int ks = 0; ks < 4; ++ks)
                Af[pt][4 + ks] = *reinterpret_cast<const f16x8*>(hBp + ks * 32 + q * 8);
        }

        float s[2][4] = {{0.f, 0.f, 0.f, 0.f}, {0.f, 0.f, 0.f, 0.f}};
        #pragma unroll
        for (int ct = 0; ct < 8; ++ct) {
            const int jj = ct * 16 + c;
            f16x8 Bfr[8];
            #pragma unroll
            for (int ks = 0; ks < 8; ++ks) {
                const int k = ks * 32 + q * 8;
                Bfr[ks] = *reinterpret_cast<const f16x8*>(
                    &w1lds[jj * 256 + (k ^ ((jj & 7) << 3))]);
            }
            #pragma unroll
            for (int pt = 0; pt < 2; ++pt) {
                f32x4 acc = {0.f, 0.f, 0.f, 0.f};
                #pragma unroll
                for (int ks = 0; ks < 8; ++ks)
                    acc = __builtin_amdgcn_mfma_f32_16x16x32_f16(Af[pt][ks],
                                                                 Bfr[ks], acc,
                                                                 0, 0, 0);
                #pragma unroll
                for (int rr = 0; rr < 4; ++rr)
                    s[pt][rr] += w2v[ct] * fast_tanh(acc[rr] + b1v[ct]);
            }
        }
        #pragma unroll
        for (int pt = 0; pt < 2; ++pt) {
            #pragma unroll
            for (int rr = 0; rr < 4; ++rr) {
                float v = s[pt][rr];
                v += __shfl_xor(v, 1);
                v += __shfl_xor(v, 2);
                v += __shfl_xor(v, 4);
                v += __shfl_xor(v, 8);
                if (c == 0) sc[(w * 2 + pt) * 16 + q * 4 + rr] = v + b2v;
            }
        }
        __syncthreads();
        // softmax over b: two groups of 64
        if (tid < 128) {
            const float sv = sc[tid];
            float m = sv;
            for (int off = 32; off; off >>= 1) m = fmaxf(m, __shfl_xor(m, off));
            const float e = __expf(sv - m);
            float sum = e;
            for (int off = 32; off; off >>= 1) sum += __shfl_xor(sum, off);
            attn[pos0 + tid] = e / sum;
        }
        __syncthreads();
    }
}

// ---------------------------------------------------------------------------
// K3b: packet_emb[n,d] = sum_l attn[l,n] * h[l,n,d]. grid 512 (4 n each), block 256.
__global__ __launch_bounds__(256) void k_packet_emb(
    const __half* __restrict__ hF, const __half* __restrict__ hB,
    const float* __restrict__ attn, float* __restrict__ pe) {
    const int tid = threadIdx.x;
    const int g = tid >> 6;          // n group
    const int lane = tid & 63;
    const int n = blockIdx.x * 4 + g;
    const bool isF = lane < 32;
    const int chunk = lane & 31;     // 4 f16 per chunk
    const __half* __restrict__ hsrc = (isF ? hF : hB) + (size_t)n * 128 + chunk * 4;
    float acc0 = 0.f, acc1 = 0.f, acc2 = 0.f, acc3 = 0.f;
    #pragma unroll 4
    for (int l = 0; l < 128; ++l) {
        const float wv = attn[l * 2048 + n];
        const uint2 u = *reinterpret_cast<const uint2*>(hsrc + (size_t)l * 2048 * 128);
        const f16* hv = reinterpret_cast<const f16*>(&u);
        acc0 = fmaf(wv, (float)hv[0], acc0);
        acc1 = fmaf(wv, (float)hv[1], acc1);
        acc2 = fmaf(wv, (float)hv[2], acc2);
        acc3 = fmaf(wv, (float)hv[3], acc3);
    }
    float4 o = {acc0, acc1, acc2, acc3};
    *reinterpret_cast<float4*>(&pe[n * 256 + (isF ? 0 : 128) + chunk * 4]) = o;
}

// ---------------------------------------------------------------------------
// K4pre: packed xg4[row*128+j] = {xr(+bhh_r), xz(+bhh_z), xn, 0}.
// grid (256,2), block 384.
__global__ __launch_bounds__(384) void k_pkt_xg(
    const float* __restrict__ pe, const float* __restrict__ wihTF,
    const float* __restrict__ bihF, const float* __restrict__ bhhF,
    const float* __restrict__ wihTB, const float* __restrict__ bihB,
    const float* __restrict__ bhhB, float4* __restrict__ xg4F,
    float4* __restrict__ xg4B) {
    const int dir = blockIdx.y;
    const float* __restrict__ wihT = dir ? wihTB : wihTF;
    const float* __restrict__ bih = dir ? bihB : bihF;
    const float* __restrict__ bhh = dir ? bhhB : bhhF;
    float4* __restrict__ xg4 = dir ? xg4B : xg4F;
    const int rbase = blockIdx.x * 8;
    __shared__ float xrow[8][256];
    __shared__ float sh[8][384];
    for (int i = threadIdx.x; i < 8 * 256; i += 384)
        xrow[i >> 8][i & 255] = pe[rbase * 256 + i];
    __syncthreads();
    const int g = threadIdx.x;
    float acc[8];
    const float bias = bih[g] + (g < 256 ? bhh[g] : 0.0f);
    #pragma unroll
    for (int r = 0; r < 8; ++r) acc[r] = bias;
    for (int d = 0; d < 256; ++d) {
        const float w = wihT[d * 384 + g];
        #pragma unroll
        for (int r = 0; r < 8; ++r) acc[r] = fmaf(w, xrow[r][d], acc[r]);
    }
    #pragma unroll
    for (int r = 0; r < 8; ++r) sh[r][g] = acc[r];
    __syncthreads();
    // pack: 8 rows x 128 float4
    for (int i = threadIdx.x; i < 8 * 128; i += 384) {
        const int r = i >> 7, jj = i & 127;
        float4 pk;
        pk.x = sh[r][jj];
        pk.y = sh[r][jj + 128];
        pk.z = sh[r][jj + 256];
        pk.w = 0.f;
        xg4[(size_t)(rbase + r) * 128 + jj] = pk;
    }
}

// ---------------------------------------------------------------------------
// K4: packet BiGRU via MFMA f16. grid 8 (dir=bx&1, chunk=bx>>1: 16 rows),
// block 512 (8 waves), 32 steps.
__global__ __launch_bounds__(512, 1) void k_pkt_gru(
    const float4* __restrict__ xg4F, const float4* __restrict__ xg4B,
    const float* __restrict__ whhF, const float* __restrict__ whhB,
    const float* __restrict__ bhhF, const float* __restrict__ bhhB,
    float* __restrict__ h2F, float* __restrict__ h2B) {
    const int dir = blockIdx.x & 1;
    const int chunk = blockIdx.x >> 1;  // 0..3
    const int row0 = chunk * 16;
    const int tid = threadIdx.x;
    const int wid = tid >> 6;
    const int lane = tid & 63;
    const int c = lane & 15;
    const int q = lane >> 4;
    const int j = wid * 16 + c;

    const float4* __restrict__ xg4 = dir ? xg4B : xg4F;
    const float* __restrict__ whh = dir ? whhB : whhF;
    const float* __restrict__ bhh = dir ? bhhB : bhhF;
    float* __restrict__ hout = dir ? h2B : h2F;

    __shared__ f16 hbuf[2][16 * 128];  // swizzled: row*128 + (k ^ ((row&7)<<3))

    for (int i = tid; i < 16 * 128; i += 512) hbuf[0][i] = (f16)0.f;

    f16x8 Bf[3][4];
    #pragma unroll
    for (int g = 0; g < 3; ++g) {
        #pragma unroll
        for (int ks = 0; ks < 4; ++ks) {
            const float* src = whh + (size_t)(g * 128 + j) * 128 + ks * 32 + q * 8;
            f16x8 b;
            #pragma unroll
            for (int e = 0; e < 8; ++e) b[e] = (f16)src[e];
            Bf[g][ks] = b;
        }
    }
    const float bh2 = bhh[j + 256];  // r,z biases folded into xg
    float hold[4];
    #pragma unroll
    for (int rr = 0; rr < 4; ++rr) hold[rr] = 0.f;
    __syncthreads();

    for (int t = 0; t < 32; ++t) {
        const int curb = t & 1, nxtb = curb ^ 1;
        const int tt = dir ? (31 - t) : t;

        float4 x4[4];
        #pragma unroll
        for (int rr = 0; rr < 4; ++rr)
            x4[rr] = xg4[(size_t)(tt * 64 + row0 + q * 4 + rr) * 128 + j];

        f16x8 Af[4];
        #pragma unroll
        for (int ks = 0; ks < 4; ++ks) {
            const int kb = ks * 32 + q * 8;
            const int idx = c * 128 + (kb ^ ((c & 7) << 3));
            Af[ks] = *reinterpret_cast<const f16x8*>(&hbuf[curb][idx]);
        }

        f32x4 a0 = {0.f, 0.f, 0.f, 0.f};
        f32x4 a1 = {0.f, 0.f, 0.f, 0.f};
        f32x4 a2 = {0.f, 0.f, 0.f, 0.f};
        #pragma unroll
        for (int ks = 0; ks < 4; ++ks) {
            a0 = __builtin_amdgcn_mfma_f32_16x16x32_f16(Af[ks], Bf[0][ks], a0, 0, 0, 0);
            a1 = __builtin_amdgcn_mfma_f32_16x16x32_f16(Af[ks], Bf[1][ks], a1, 0, 0, 0);
            a2 = __builtin_amdgcn_mfma_f32_16x16x32_f16(Af[ks], Bf[2][ks], a2, 0, 0, 0);
        }

        #pragma unroll
        for (int rr = 0; rr < 4; ++rr) {
            const float rg = fast_sigmoid(x4[rr].x + a0[rr]);
            const float zg = fast_sigmoid(x4[rr].y + a1[rr]);
            const float ng = fast_tanh(x4[rr].z + rg * (a2[rr] + bh2));
            const float hn = fmaf(zg, hold[rr] - ng, ng);
            hold[rr] = hn;
            const int row = q * 4 + rr;
            hbuf[nxtb][row * 128 + (j ^ ((row & 7) << 3))] = (f16)hn;
            hout[((size_t)tt * 64 + row0 + row) * 128 + j] = hn;
        }
        lds_barrier();
    }
}

// ---------------------------------------------------------------------------
// K5a: packet attention scores. grid 2048 (n), block 128.
__global__ __launch_bounds__(128) void k_scores2(
    const float* __restrict__ h2F, const float* __restrict__ h2B,
    const float* __restrict__ paw1,  // [128][256] row-major
    const float* __restrict__ pab1, const float* __restrict__ paw2,
    const float* __restrict__ pab2, float* __restrict__ scores2) {
    const int n = blockIdx.x;
    const int tid = threadIdx.x;  // 128
    __shared__ float x[256];
    __shared__ float red[2];
    x[tid] = h2F[n * 128 + tid];
    x[tid + 128] = h2B[n * 128 + tid];
    __syncthreads();
    float acc = pab1[tid];
    const float* wr = paw1 + tid * 256;
    #pragma unroll 8
    for (int d = 0; d < 256; ++d) acc = fmaf(wr[d], x[d], acc);
    float s = paw2[tid] * fast_tanh(acc);
    s += __shfl_xor(s, 1);
    s += __shfl_xor(s, 2);
    s += __shfl_xor(s, 4);
    s += __shfl_xor(s, 8);
    s += __shfl_xor(s, 16);
    s += __shfl_xor(s, 32);
    if ((tid & 63) == 0) red[tid >> 6] = s;
    __syncthreads();
    if (tid == 0) scores2[n] = red[0] + red[1] + pab2[0];
}

// ---------------------------------------------------------------------------
// K5b: softmax over b + weighted sum + final FC. grid 32 (p), block 256.
__global__ __launch_bounds__(256) void k_final3(
    const float* __restrict__ h2F, const float* __restrict__ h2B,
    const float* __restrict__ scores2, const float* __restrict__ wf,
    const float* __restrict__ bfv, float* __restrict__ outp) {
    const int p = blockIdx.x;
    const int tid = threadIdx.x;
    __shared__ float sc[64];
    __shared__ float femb[256];
    __shared__ float red[64];

    if (tid < 64) {
        const float s = scores2[p * 64 + tid];
        float m = s;
        for (int off = 32; off; off >>= 1) m = fmaxf(m, __shfl_xor(m, off));
        const float e = __expf(s - m);
        float sum = e;
        for (int off = 32; off; off >>= 1) sum += __shfl_xor(sum, off);
        sc[tid] = e / sum;
    }
    __syncthreads();

    {
        const float* __restrict__ hsrc = (tid < 128) ? h2F : h2B;
        const int d = tid & 127;
        float acc = 0.f;
        for (int b = 0; b < 64; ++b)
            acc = fmaf(sc[b], hsrc[(p * 64 + b) * 128 + d], acc);
        femb[tid] = acc;
    }
    __syncthreads();

    const float fv = femb[tid];
    #pragma unroll
    for (int c = 0; c < 10; ++c) {
        float s = fv * wf[c * 256 + tid];
        s += __shfl_xor(s, 1);
        s += __shfl_xor(s, 2);
        s += __shfl_xor(s, 4);
        s += __shfl_xor(s, 8);
        s += __shfl_xor(s, 16);
        s += __shfl_xor(s, 32);
        if ((tid & 63) == 0) red[(c << 2) | (tid >> 6)] = s;
        __syncthreads();
        if (tid == 0)
            outp[p * 10 + c] = bfv[c] + red[c << 2] + red[(c << 2) | 1] +
                               red[(c << 2) | 2] + red[(c << 2) | 3];
        __syncthreads();
    }
}

// ---------------------------------------------------------------------------
extern "C" void kernel_launch(void* const* d_in, const int* in_sizes, int n_in,
                              void* d_out, int out_size, void* d_ws,
                              size_t ws_size, hipStream_t stream) {
    const int* flow = (const int*)d_in[0];
    const float* emb = (const float*)d_in[1];
    const float* byte_wih_f = (const float*)d_in[2];
    const float* byte_whh_f = (const float*)d_in[3];
    const float* byte_bih_f = (const float*)d_in[4];
    const float* byte_bhh_f = (const float*)d_in[5];
    const float* byte_wih_b = (const float*)d_in[6];
    const float* byte_whh_b = (const float*)d_in[7];
    const float* byte_bih_b = (const float*)d_in[8];
    const float* byte_bhh_b = (const float*)d_in[9];
    const float* pkt_wih_f = (const float*)d_in[10];
    const float* pkt_whh_f = (const float*)d_in[11];
    const float* pkt_bih_f = (const float*)d_in[12];
    const float* pkt_bhh_f = (const float*)d_in[13];
    const float* pkt_wih_b = (const float*)d_in[14];
    const float* pkt_whh_b = (const float*)d_in[15];
    const float* pkt_bih_b = (const float*)d_in[16];
    const float* pkt_bhh_b = (const float*)d_in[17];
    const float* ba_w1 = (const float*)d_in[18];
    const float* ba_b1 = (const float*)d_in[19];
    const float* ba_w2 = (const float*)d_in[20];
    const float* ba_b2 = (const float*)d_in[21];
    const float* pa_w1 = (const float*)d_in[22];
    const float* pa_b1 = (const float*)d_in[23];
    const float* pa_w2 = (const float*)d_in[24];
    const float* pa_b2 = (const float*)d_in[25];
    const float* wf = (const float*)d_in[26];
    const float* bf = (const float*)d_in[27];

    char* base = (char*)d_ws;
    size_t off = 0;
    auto allocf = [&](size_t nf) -> float* {
        float* p = (float*)(base + off);
        off += nf * sizeof(float);
        return p;
    };
    auto alloch = [&](size_t nh) -> __half* {
        off = (off + 255) & ~(size_t)255;
        __half* p = (__half*)(base + off);
        off += nh * sizeof(__half);
        return p;
    };
    float* wihTpF = allocf(256 * 384);
    float* wihTpB = allocf(256 * 384);
    float* attn = allocf(262144);
    float* pe = allocf(2048 * 256);
    float4* tab4F = (float4*)allocf(256 * 128 * 4);
    float4* tab4B = (float4*)allocf(256 * 128 * 4);
    float4* xg4F = (float4*)allocf((size_t)2048 * 128 * 4);
    float4* xg4B = (float4*)allocf((size_t)2048 * 128 * 4);
    float* h2F = allocf(32 * 64 * 128);
    float* h2B = allocf(32 * 64 * 128);
    float* scores2 = allocf(2048);
    __half* hF = alloch((size_t)128 * 2048 * 128);
    __half* hB = alloch((size_t)128 * 2048 * 128);
    if (off > ws_size) return;  // diagnostic: leaves d_out poisoned
    (void)in_sizes; (void)n_in; (void)out_size;

    k_tables<<<512, 384, 0, stream>>>(emb, byte_wih_f, byte_bih_f, byte_bhh_f,
                                      byte_wih_b, byte_bih_b, byte_bhh_b,
                                      tab4F, tab4B);

    TransArgs ta;
    ta.src[0] = pkt_wih_f; ta.dst[0] = wihTpF; ta.R[0] = 384; ta.C[0] = 256;
    ta.src[1] = pkt_wih_b; ta.dst[1] = wihTpB; ta.R[1] = 384; ta.C[1] = 256;
    k_transpose<<<dim3(96, 2), 256, 0, stream>>>(ta);

    k_byte_gru<<<256, 512, 0, stream>>>(flow, tab4F, tab4B, byte_whh_f,
                                        byte_whh_b, byte_bhh_f, byte_bhh_b, hF,
                                        hB);

    k_scores_attn<<<512, 256, 0, stream>>>(hF, hB, ba_w1, ba_b1, ba_w2, ba_b2,
                                           attn);
    k_packet_emb<<<512, 256, 0, stream>>>(hF, hB, attn, pe);

    k_pkt_xg<<<dim3(256, 2), 384, 0, stream>>>(pe, wihTpF, pkt_bih_f,
                                               pkt_bhh_f, wihTpB, pkt_bih_b,
                                               pkt_bhh_b, xg4F, xg4B);
    k_pkt_gru<<<8, 512, 0, stream>>>(xg4F, xg4B, pkt_whh_f, pkt_whh_b,
                                     pkt_bhh_f, pkt_bhh_b, h2F, h2B);
    k_scores2<<<2048, 128, 0, stream>>>(h2F, h2B, pa_w1, pa_b1, pa_w2, pa_b2,
                                        scores2);
    k_final3<<<32, 256, 0, stream>>>(h2F, h2B, scores2, wf, bf, (float*)d_out);
}